// Round 10
// baseline (296.847 us; speedup 1.0000x reference)
//
#include <hip/hip_runtime.h>

#define SEQ_T   2048
#define BATCH_N 4096
#define LOG2E   1.4426950408889634f
#define PF      8

// DPP helpers. Chain group = 16 lanes = one DPP row (groups are 16-aligned).
//   quad_perm 0xB1 = (1,0,3,2): swap within pair (p exchange)
//   quad_perm 0x4E = (2,3,0,1): lane^2 -> unit^1
//   ROW_HALF_MIRROR 0x141: l->7-l within 8 -> unit^3 (p flips; h is p-uniform)
//   ROW_ROR:8 0x128: l -> l+8 mod 16 (symmetric): L0 half <-> L1 half
#define DPPF(v, ctrl) __int_as_float(__builtin_amdgcn_mov_dpp(__float_as_int(v), (ctrl), 0xF, 0xF, true))
// update_dpp with bank_mask 0xC: only lanes 8..15 of each row take the DPP
// value; lanes 0..7 keep `oldv`. One inst = route x (L0) + transfer h0 (L1).
#define XFER(oldv, srcv) __int_as_float(__builtin_amdgcn_update_dpp( \
    __float_as_int(oldv), __float_as_int(srcv), 0x128, 0xF, 0xC, false))

// Mapping: 16 lanes per chain. lanes 0-7 = layer0 step k, lanes 8-15 = layer1
// step k-1 (skewed). Within 8: l3 = 2*u + p. p=0 owns gate rows {i_u, g_u},
// p=1 owns {f_u, o_u} (PyTorch rows: i=0+u, f=4+u, g=8+u, o=12+u).
// Each lane computes 2 pre-activations (A = i/f row, B = g/o row).
// 4096 chains * 16 lanes = 1024 waves = 1 wave/SIMD. No LDS, no barriers.
__global__ __launch_bounds__(256, 1) void lstm2_fused8(
    const float* __restrict__ x,
    const float* __restrict__ Wih0, const float* __restrict__ Whh0,
    const float* __restrict__ bih0, const float* __restrict__ bhh0,
    const float* __restrict__ Wih1, const float* __restrict__ Whh1,
    const float* __restrict__ bih1, const float* __restrict__ bhh1,
    float* __restrict__ out)
{
    const int tid   = blockIdx.x * blockDim.x + threadIdx.x;
    const int g16   = tid & 15;
    const int chain = tid >> 4;
    const int l3    = g16 & 7;
    const int u     = l3 >> 1;            // hidden unit
    const int p     = l3 & 1;             // 0: {i,g}, 1: {f,o}
    const bool isL1 = (g16 >= 8);
    const bool pse  = (p != 0);           // loop-invariant cndmask masks
    const int rowA  = (p ? 4 : 0) + u;    // i or f
    const int rowB  = (p ? 12 : 8) + u;   // g or o

    const float* WI = isL1 ? Wih1 : Wih0;
    const float* WH = isL1 ? Whh1 : Whh0;
    const float* BI = isL1 ? bih1 : bih0;
    const float* BH = isL1 ? bhh1 : bhh0;

    const float csc = -2.0f * LOG2E;           // cell-tanh arg scale (folded)
    const float scA = -LOG2E;                  // sigmoid rows (i, f)
    const float scB = p ? -LOG2E : csc;        // o: sigmoid; g: tanh(2x trick)

    // Input-dot operand order: L0 sees x in natural order; L1 sees h0 in
    // u-relative order (slot d = h0_{u^d}). Recurrent dots always u-relative.
    float winA[4], winB[4], whhA[4], whhB[4];
#pragma unroll
    for (int d = 0; d < 4; ++d) {
        const int di = isL1 ? (u ^ d) : d;
        winA[d] = WI[rowA * 4 + di]      * scA;
        winB[d] = WI[rowB * 4 + di]      * scB;
        whhA[d] = WH[rowA * 4 + (u ^ d)] * scA;
        whhB[d] = WH[rowB * 4 + (u ^ d)] * scB;
    }
    const float bA = (BI[rowA] + BH[rowA]) * scA;
    const float bB = (BI[rowB] + BH[rowB]) * scB;
    // B-row activation epilogue: g-row (p=0): a = csc*tanh(pre) = 2csc*s - csc
    //                            o-row (p=1): a = s
    const float kaB = p ? 1.0f : 2.0f * csc;
    const float kbB = p ? 0.0f : -csc;

    const char* __restrict__ xb = (const char*)x;
    char* __restrict__ ob = (char*)out;
    const unsigned xhome = (unsigned)chain * 16u;
    const unsigned XCL   = xhome + 2047u * 65536u;
    unsigned ooff = (unsigned)(chain * 16 + u * 4);   // out[0][chain][u]

    // state (per lane's layer): h + u-relative mirrors, pre-scaled cell
    float h = 0.f, ha = 0.f, hb2 = 0.f, hc = 0.f, cs = 0.f;

    // ---- one fused step: L0 lanes advance with input x(t); L1 lanes advance
    //      with input h0(prev) arriving via XFER. Updates h/mirrors/cs. ----
    auto step = [&](const float4 xv) {
        // operand routing: L0 keeps x components, L1 receives h0 mirrors
        float i0 = XFER(xv.x, h);
        float i1 = XFER(xv.y, ha);
        float i2 = XFER(xv.z, hb2);
        float i3 = XFER(xv.w, hc);
        // two dots per lane (rows A and B)
        float accA = fmaf(winA[0], i0, fmaf(winA[1], i1,
                     fmaf(winA[2], i2, fmaf(winA[3], i3, bA))));
        float accB = fmaf(winB[0], i0, fmaf(winB[1], i1,
                     fmaf(winB[2], i2, fmaf(winB[3], i3, bB))));
        accA = fmaf(whhA[0], h, fmaf(whhA[1], ha,
               fmaf(whhA[2], hb2, fmaf(whhA[3], hc, accA))));
        accB = fmaf(whhB[0], h, fmaf(whhB[1], ha,
               fmaf(whhB[2], hb2, fmaf(whhB[3], hc, accB))));
        // activations (paired so the two trans chains pipeline)
        float eA = __builtin_amdgcn_exp2f(accA);
        float eB = __builtin_amdgcn_exp2f(accB);
        float sA = __builtin_amdgcn_rcpf(1.0f + eA);   // i or f
        float sB = __builtin_amdgcn_rcpf(1.0f + eB);
        float aB = fmaf(kaB, sB, kbB);                 // csc*tanh(g) or o
        // cell update: cs = f*cs + (i*g)*csc, via one pair exchange
        float P  = sA * aB;                 // p0: i*g*csc   (p1: f*o, unused)
        float sh = pse ? sA : P;            // p0 shares P, p1 shares f
        float w  = DPPF(sh, 0xB1);          // cross-pair value
        float fv = pse ? sA : w;
        float Pv = pse ? w  : P;
        cs = fmaf(fv, cs, Pv);
        // h = o * tanh(c);  z = exp2(cs) = e^{-2c}
        float z  = __builtin_amdgcn_exp2f(cs);
        float t2 = fmaf(2.0f, __builtin_amdgcn_rcpf(1.0f + z), -1.0f);
        float os = DPPF(aB, 0xB1);          // p0 fetches o from p1
        float ov = pse ? aB : os;
        h  = ov * t2;
        // u-relative mirrors for next step's dots
        ha  = DPPF(h, 0x4E);                // u^1
        hc  = DPPF(h, 0x141);               // u^3
        hb2 = DPPF(hc, 0x4E);               // u^2
    };

    // ---- x prefetch ring: x(0..PF-1) ----
    float4 xbuf[PF];
    unsigned xoff = xhome;
#pragma unroll
    for (int i = 0; i < PF; ++i) {
        xbuf[i] = *(const float4*)(xb + xoff);
        xoff += 65536u;
    }

    // ---- peel k=0: L0 computes h0(0); L1 computes junk -> reset ----
    {
        const float4 xv = xbuf[0];
        unsigned off = (xoff < XCL) ? xoff : XCL;
        xbuf[0] = *(const float4*)(xb + off);
        xoff += 65536u;
        step(xv);
        h   = isL1 ? 0.f : h;
        ha  = isL1 ? 0.f : ha;
        hb2 = isL1 ? 0.f : hb2;
        hc  = isL1 ? 0.f : hc;
        cs  = isL1 ? 0.f : cs;
    }

    // ---- main: k = 1..2048; L0 step k, L1 step k-1; store h1(k-1) ----
    const bool dostore = isL1 && (p == 0);   // lanes 8,10,12,14: h = h1_u
    for (int kk = 1; kk <= SEQ_T; kk += PF) {
#pragma unroll
        for (int q = 0; q < PF; ++q) {
            const int slot = (q + 1) & (PF - 1);
            const float4 xv = xbuf[slot];
            unsigned off = (xoff < XCL) ? xoff : XCL;
            xbuf[slot] = *(const float4*)(xb + off);
            xoff += 65536u;
            step(xv);
            if (dostore) {
                *(float*)(ob + ooff) = h;
            }
            ooff += 65536u;
        }
    }
}

extern "C" void kernel_launch(void* const* d_in, const int* in_sizes, int n_in,
                              void* d_out, int out_size, void* d_ws, size_t ws_size,
                              hipStream_t stream) {
    const float* x    = (const float*)d_in[0];
    const float* Wih0 = (const float*)d_in[1];
    const float* Whh0 = (const float*)d_in[2];
    const float* bih0 = (const float*)d_in[3];
    const float* bhh0 = (const float*)d_in[4];
    const float* Wih1 = (const float*)d_in[5];
    const float* Whh1 = (const float*)d_in[6];
    const float* bih1 = (const float*)d_in[7];
    const float* bhh1 = (const float*)d_in[8];
    float* out = (float*)d_out;

    // 4096 chains * 16 lanes (8 L0 + 8 L1) = 1024 waves = 1 wave/SIMD
    dim3 grid(256), block(256);
    hipLaunchKernelGGL(lstm2_fused8, grid, block, 0, stream,
                       x, Wih0, Whh0, bih0, bhh0, Wih1, Whh1, bih1, bhh1, out);
}